// Round 18
// baseline (250.109 us; speedup 1.0000x reference)
//
#include <hip/hip_runtime.h>
#include <float.h>
#include <stdint.h>
#include <stddef.h>

#define D_DIM 512
// Pure bf16 hi*hi score; err = 2(e_z.c + zh.e_c), sigma ~ 0.108,
// pairwise-delta sigma ~ 0.153. MARGIN = 1.5 ~ 9.8 sigma -> miss prob ~1e-9.
#define MARGIN 1.5f

typedef unsigned short ushort_t;
typedef unsigned int u32;
typedef __attribute__((ext_vector_type(8))) short short8v;     // 8 bf16 (4 VGPRs)
typedef __attribute__((ext_vector_type(8))) unsigned short ushort8v;
typedef __attribute__((ext_vector_type(4))) float f32x4;

__device__ __forceinline__ ushort_t f32_bf16_rne(float x) {
    u32 u = __float_as_uint(x);
    u32 r = (u + 0x7fffu + ((u >> 16) & 1u)) >> 16;
    return (ushort_t)r;
}
__device__ __forceinline__ void gload_lds16(const void* g, void* l) {
    __builtin_amdgcn_global_load_lds(
        (const __attribute__((address_space(1))) u32*)(g),
        (__attribute__((address_space(3))) u32*)(l), 16, 0, 0);
}

// ============ prep: z -> bf16 hi ===========================================
__global__ __launch_bounds__(256) void split_z_kernel(const float* __restrict__ z,
                                                      ushort_t* __restrict__ z_hi,
                                                      long total8) {
    long i = (long)blockIdx.x * 256 + threadIdx.x;
    if (i >= total8) return;
    const float4* p = (const float4*)(z + i * 8);
    float4 a = p[0], b = p[1];
    float x[8] = {a.x, a.y, a.z, a.w, b.x, b.y, b.z, b.w};
    ushort8v h;
    #pragma unroll
    for (int j = 0; j < 8; ++j) h[j] = f32_bf16_rne(x[j]);
    *(ushort8v*)(z_hi + i * 8) = h;
}

// ============ prep: codebook hi (bf16) + norms (f32/f64) + zero freq =======
__global__ __launch_bounds__(256) void split_cb_kernel(const float* __restrict__ cb,
                                                       ushort_t* __restrict__ cb_hi,
                                                       float* __restrict__ csq32,
                                                       double* __restrict__ csq64,
                                                       float* __restrict__ freq,
                                                       int K) {
    int tid = threadIdx.x;
    int gt = blockIdx.x * 256 + tid;
    if (gt < K) freq[gt] = 0.0f;

    int wv = tid >> 6, lane = tid & 63;
    int k = blockIdx.x * 4 + wv;
    if (k >= K) return;
    const float* row = cb + (size_t)k * D_DIM;
    float4 a = *(const float4*)(row + lane * 8);
    float4 b = *(const float4*)(row + lane * 8 + 4);
    float x[8] = {a.x, a.y, a.z, a.w, b.x, b.y, b.z, b.w};
    ushort8v h;
    double s = 0.0;
    #pragma unroll
    for (int j = 0; j < 8; ++j) {
        s += (double)x[j] * x[j];
        h[j] = f32_bf16_rne(x[j]);
    }
    *(ushort8v*)(cb_hi + (size_t)k * D_DIM + lane * 8) = h;
    #pragma unroll
    for (int off = 32; off > 0; off >>= 1) s += __shfl_down(s, off);
    if (lane == 0) { csq64[k] = s; csq32[k] = (float)s; }
}

// ============ pass 1: bf16 MFMA GEMM + per-(row,half) candidates ===========
// R18: 256-thread blocks (4 waves 2x2, wave tile 64x64), 128x128 tile,
// 2 LDS buffers x 32KB = 64KB -> 2 blocks/CU (independent barrier domains
// cover each other's vmcnt/barrier drains). Grid (N/128, 2) = 512 blocks.
// Per step (R16 counted-vmcnt schedule, compile-time buffer parity):
//   [barrier] STAGE(next)->other buf   (WAR-safe)
//   vmcnt(8) (drain own stage; the 8 just-issued stay in flight) [barrier]
//   COMPUTE(cur)
__global__ __launch_bounds__(256, 2) void pass1_mfma_kernel(
        const ushort_t* __restrict__ z_hi, const ushort_t* __restrict__ cb_hi,
        const float* __restrict__ csq32,
        float* __restrict__ cm_v0, int* __restrict__ cm_cnt,
        u32* __restrict__ cm_mask,
        float* __restrict__ cand_v, int* __restrict__ cand_k, int K) {
    extern __shared__ char smem[];
    const int tid = threadIdx.x;           // 0..255
    const int wid = tid >> 6;              // 0..3
    const int lane = tid & 63;
    const int wm = wid >> 1, wn = wid & 1; // wave grid 2x2 (64x64 tiles)
    const int c = lane & 15, g = lane >> 4;
    const int row0 = blockIdx.x * 128;
    const int half = blockIdx.y;

    // staging byte offsets (swizzle pre-applied to source)
    // A: 128 rows x 8 slots = 1024 slots, 4/thread; B: 128 codes, 4/thread
    u32 stg[4];
    #pragma unroll
    for (int r = 0; r < 4; ++r) {
        int s = r * 256 + tid, rw = s >> 3, p = s & 7;
        stg[r] = (u32)(rw * 1024 + ((p ^ (rw & 7)) << 4));
    }
    // ds_read byte offsets, both k-slots precomputed
    u32 rdA[2][4], rdB[2][4];
    #pragma unroll
    for (int f = 0; f < 4; ++f) {
        int rl = wm * 64 + f * 16 + c;                 // 0..127
        rdA[0][f] = (u32)(rl * 128 + ((g ^ (rl & 7)) << 4));
        rdA[1][f] = rdA[0][f] ^ 64u;
        int cl = wn * 64 + f * 16 + c;                 // 0..127
        rdB[0][f] = (u32)(cl * 128 + ((g ^ (cl & 7)) << 4));
        rdB[1][f] = rdB[0][f] ^ 64u;
    }

    const char* pA = (const char*)z_hi + (size_t)row0 * 1024;
    const char* pB = (const char*)cb_hi + (size_t)half * 2048 * 1024;

    // after staging chunk 7: next stage is chunk 0 of the NEXT code tile
    const ptrdiff_t eA7 = -896;            // zh+896 -> zh+0 (A reused per ct)
    const ptrdiff_t eB7 = 131072 - 896;    // ch+896 -> next-ct ch+0 (+128 codes)

    f32x4 acc[4][4];
    float tv0[16], tv1[16]; int tk0[16];
    #pragma unroll
    for (int i = 0; i < 16; ++i) { tv0[i] = FLT_MAX; tv1[i] = FLT_MAX; tk0[i] = 0; }

    auto STAGE = [&](int buf) {
        char* base = smem + buf * 32768;
        #pragma unroll
        for (int r = 0; r < 4; ++r)
            gload_lds16(pA + stg[r], base + r * 4096 + wid * 1024);
        #pragma unroll
        for (int r = 0; r < 4; ++r)
            gload_lds16(pB + stg[r], base + 16384 + r * 4096 + wid * 1024);
    };
    auto COMPUTE = [&](int buf) {
        const char* Abase = smem + buf * 32768;
        const char* Bb = Abase + 16384;
        #pragma unroll
        for (int ks = 0; ks < 2; ++ks) {
            short8v a[4], b[4];
            #pragma unroll
            for (int f = 0; f < 4; ++f) a[f] = *(const short8v*)(Abase + rdA[ks][f]);
            #pragma unroll
            for (int f = 0; f < 4; ++f) b[f] = *(const short8v*)(Bb + rdB[ks][f]);
            #pragma unroll
            for (int fm = 0; fm < 4; ++fm)
                #pragma unroll
                for (int fn = 0; fn < 4; ++fn)
                    acc[fm][fn] = __builtin_amdgcn_mfma_f32_16x16x32_bf16(
                        a[fm], b[fn], acc[fm][fn], 0, 0, 0);
        }
    };
    auto BARA = [&]() {
        __builtin_amdgcn_s_barrier();
        __builtin_amdgcn_sched_barrier(0);
    };
    auto WAITBARB = [&]() {
        asm volatile("s_waitcnt vmcnt(8)" ::: "memory");
        __builtin_amdgcn_s_barrier();
        __builtin_amdgcn_sched_barrier(0);
    };

    // prologue: stage chunk 0 -> buf0
    STAGE(0); pA += 128; pB += 128;

    #pragma unroll 1
    for (int ci = 0; ci < 16; ++ci) {
        int code0 = (half * 16 + ci) << 7;
        float cq[4];
        #pragma unroll
        for (int fn = 0; fn < 4; ++fn) cq[fn] = csq32[code0 + wn * 64 + fn * 16 + c];

        f32x4 zz = {0.f, 0.f, 0.f, 0.f};
        #pragma unroll
        for (int fm = 0; fm < 4; ++fm)
            #pragma unroll
            for (int fn = 0; fn < 4; ++fn) acc[fm][fn] = zz;

        // 8 steps = 4 pairs; ct-advance after staging chunk 7 (tp=3 even).
        #pragma unroll 1
        for (int tp = 0; tp < 4; ++tp) {
            // even step t=2tp: stage chunk 2tp+1 -> buf1, compute buf0
            BARA();
            STAGE(1);
            { ptrdiff_t dA = 128, dB = 128;
              if (tp == 3) { dA = eA7; dB = eB7; }
              pA += dA; pB += dB; }
            WAITBARB();
            COMPUTE(0);
            // odd step t=2tp+1: stage chunk 2tp+2 -> buf0, compute buf1
            BARA();
            STAGE(0);
            pA += 128; pB += 128;
            WAITBARB();
            COMPUTE(1);
        }
        // (tp=3 odd step staged chunk0 of next ct; for ci==15 it reads
        //  in-bounds trailing ws data that is never consumed)

        // ---- epilogue: scores + branchless top-2 value + top-1 index ----
        #pragma unroll
        for (int fm = 0; fm < 4; ++fm)
            #pragma unroll
            for (int fn = 0; fn < 4; ++fn) {
                int code = code0 + wn * 64 + fn * 16 + c;
                #pragma unroll
                for (int rg = 0; rg < 4; ++rg) {
                    int rp = fm * 4 + rg;
                    float sv = fmaf(-2.0f, acc[fm][fn][rg], cq[fn]);
                    bool b0 = sv < tv0[rp];
                    bool b1 = sv < tv1[rp];
                    tv1[rp] = b0 ? tv0[rp] : (b1 ? sv : tv1[rp]);
                    tv0[rp] = b0 ? sv : tv0[rp];
                    tk0[rp] = b0 ? code : tk0[rp];
                }
            }
    }

    // ---- merge 32 slots/row (top-1 idx + top-2 values) for this half ----
    __syncthreads();                       // full drain (incl. tail stage)
    float* mv = (float*)smem;              // [128][64]: even=v0, odd=v1 (32KB)
    int*   mi = (int*)(smem + 32768);      // [128][32]: top-1 codes (16KB)
    #pragma unroll
    for (int fm = 0; fm < 4; ++fm)
        #pragma unroll
        for (int rg = 0; rg < 4; ++rg) {
            int rl = wm * 64 + fm * 16 + g * 4 + rg;   // C row mapping 0..127
            int slot = wn * 16 + c;                    // 0..31
            int rp = fm * 4 + rg;
            mv[rl * 64 + slot * 2]     = tv0[rp];
            mv[rl * 64 + slot * 2 + 1] = tv1[rp];
            mi[rl * 32 + slot]         = tk0[rp];
        }
    __syncthreads();
    if (tid < 128) {
        const float* rv = mv + tid * 64;
        const int*   ri = mi + tid * 32;
        float v0 = FLT_MAX;
        #pragma unroll 8
        for (int j = 0; j < 32; ++j) v0 = fminf(v0, rv[2 * j]);
        float lim = v0 + MARGIN;
        u32 mask = 0;
        int cnt = 0; int ks[8]; float vs[8];
        for (int j = 0; j < 32; ++j) {
            if (rv[2 * j] <= lim) {
                if (cnt < 8) { ks[cnt] = ri[j]; vs[cnt] = rv[2 * j]; cnt++; }
                else mask |= 1u << j;      // overflow: rescan this slot
            }
            if (rv[2 * j + 1] <= lim) mask |= 1u << j;  // slot-second in margin
        }
        int gidx = (row0 + tid) * 2 + half;
        cm_v0[gidx]  = v0;
        cm_cnt[gidx] = cnt;                // always 1..8
        cm_mask[gidx] = mask;
        for (int m = 0; m < cnt; ++m) {
            cand_v[(size_t)gidx * 8 + m] = vs[m];
            cand_k[(size_t)gidx * 8 + m] = ks[m];
        }
    }
}

// ============ pass 2: merge halves, f64 rescore (cands + suspect slots) ====
__global__ __launch_bounds__(256) void pass2_new_kernel(
        const float* __restrict__ z, const float* __restrict__ cb,
        const double* __restrict__ csq64,
        const float* __restrict__ cm_v0, const int* __restrict__ cm_cnt,
        const u32* __restrict__ cm_mask,
        const float* __restrict__ cand_v, const int* __restrict__ cand_k,
        float* __restrict__ zq, float* __restrict__ oidx, float* __restrict__ freq,
        int N, int K) {
    int lane = threadIdx.x & 63;
    int row = blockIdx.x * 4 + (threadIdx.x >> 6);
    if (row >= N) return;
    const int Khalf = K >> 1;              // 2048

    float v0a = cm_v0[row * 2], v0b = cm_v0[row * 2 + 1];
    int   na  = cm_cnt[row * 2], nb = cm_cnt[row * 2 + 1];
    u32   ma  = cm_mask[row * 2], mb = cm_mask[row * 2 + 1];
    float lim = fminf(v0a, v0b) + MARGIN;
    if (na > 8 || na < 0) { na = 0; ma = 0xffffffffu; }   // defensive
    if (nb > 8 || nb < 0) { nb = 0; mb = 0xffffffffu; }

    // collect stored candidates <= global lim
    int ks[16]; int cnt = 0;
    {
        for (int m = 0; m < na; ++m) {
            size_t idx = (size_t)(row * 2) * 8 + m;
            if (cand_v[idx] <= lim) ks[cnt++] = cand_k[idx];
        }
        for (int m = 0; m < nb; ++m) {
            size_t idx = (size_t)(row * 2 + 1) * 8 + m;
            if (cand_v[idx] <= lim) ks[cnt++] = cand_k[idx];
        }
    }

    int best_k;
    if (cnt == 1 && ma == 0 && mb == 0) {
        best_k = ks[0];                    // exact within margin model
    } else {
        const float* zrow = z + (size_t)row * D_DIM;
        double best_s = DBL_MAX; int bk = 0x7fffffff;

        // phase 1: rescore candidate list (64-lane d-split per code)
        {
            float4 z0 = *(const float4*)(zrow + lane * 4);
            float4 z1 = *(const float4*)(zrow + 256 + lane * 4);
            for (int m = 0; m < cnt; ++m) {
                int k = ks[m];
                const float* crow = cb + (size_t)k * D_DIM;
                float4 c0 = *(const float4*)(crow + lane * 4);
                float4 c1 = *(const float4*)(crow + 256 + lane * 4);
                double a = (double)z0.x * c0.x + (double)z0.y * c0.y +
                           (double)z0.z * c0.z + (double)z0.w * c0.w +
                           (double)z1.x * c1.x + (double)z1.y * c1.y +
                           (double)z1.z * c1.z + (double)z1.w * c1.w;
                #pragma unroll
                for (int off = 32; off > 0; off >>= 1) a += __shfl_down(a, off);
                if (lane == 0) {
                    double s = csq64[k] - 2.0 * a;
                    if (s < best_s || (s == best_s && k < bk)) { best_s = s; bk = k; }
                }
            }
            best_s = __shfl(best_s, 0);
            bk     = __shfl(bk, 0);
        }

        // phase 2: rescan suspect slots (64 codes each; 8 codes x 8 lanes)
        if (ma | mb) {
            const int cs = lane >> 3;      // code sub-index 0..7
            const int ds = lane & 7;       // d-chunk 0..7 (64 floats each)
            const float* zch = zrow + ds * 64;
            float4 zr[16];
            #pragma unroll
            for (int j = 0; j < 16; ++j) zr[j] = *(const float4*)(zch + j * 4);

            double bs2 = DBL_MAX; int bk2 = 0x7fffffff;
            for (int h = 0; h < 2; ++h) {
                u32 m = h ? mb : ma;
                while (m) {
                    int s = __ffs(m) - 1; m &= m - 1;
                    for (int tb = 0; tb < 8; ++tb) {
                        int t = tb * 8 + cs;                       // 0..63
                        int code = h * Khalf + ((t >> 2) << 7) + ((s >> 4) << 6)
                                 + ((t & 3) << 4) + (s & 15);
                        const float* crow = cb + (size_t)code * D_DIM + ds * 64;
                        double a0 = 0.0, a1 = 0.0, a2 = 0.0, a3 = 0.0;
                        #pragma unroll
                        for (int j = 0; j < 16; j += 4) {
                            float4 c0 = *(const float4*)(crow + j * 4);
                            float4 c1 = *(const float4*)(crow + j * 4 + 4);
                            float4 c2 = *(const float4*)(crow + j * 4 + 8);
                            float4 c3 = *(const float4*)(crow + j * 4 + 12);
                            a0 += (double)zr[j].x * c0.x + (double)zr[j].y * c0.y +
                                  (double)zr[j].z * c0.z + (double)zr[j].w * c0.w;
                            a1 += (double)zr[j+1].x * c1.x + (double)zr[j+1].y * c1.y +
                                  (double)zr[j+1].z * c1.z + (double)zr[j+1].w * c1.w;
                            a2 += (double)zr[j+2].x * c2.x + (double)zr[j+2].y * c2.y +
                                  (double)zr[j+2].z * c2.z + (double)zr[j+2].w * c2.w;
                            a3 += (double)zr[j+3].x * c3.x + (double)zr[j+3].y * c3.y +
                                  (double)zr[j+3].z * c3.z + (double)zr[j+3].w * c3.w;
                        }
                        double a = (a0 + a1) + (a2 + a3);
                        #pragma unroll
                        for (int off = 1; off < 8; off <<= 1) a += __shfl_xor(a, off);
                        double sc = csq64[code] - 2.0 * a;
                        if (sc < bs2 || (sc == bs2 && code < bk2)) { bs2 = sc; bk2 = code; }
                    }
                }
            }
            #pragma unroll
            for (int off = 32; off > 0; off >>= 1) {
                double os = __shfl_down(bs2, off);
                int    ok2 = __shfl_down(bk2, off);
                if (os < bs2 || (os == bs2 && ok2 < bk2)) { bs2 = os; bk2 = ok2; }
            }
            bs2 = __shfl(bs2, 0);
            bk2 = __shfl(bk2, 0);
            if (bs2 < best_s || (bs2 == best_s && bk2 < bk)) { best_s = bs2; bk = bk2; }
        }
        best_k = bk;
    }

    if (lane == 0) {
        oidx[row] = (float)best_k;
        atomicAdd(&freq[best_k], 1.0f);
    }
    // gather z_q = codebook[best_k] (exact -> bitwise match)
    const float* crow = cb + (size_t)best_k * D_DIM;
    *(float4*)(zq + (size_t)row * D_DIM + lane * 4) = *(const float4*)(crow + lane * 4);
    *(float4*)(zq + (size_t)row * D_DIM + 256 + lane * 4) = *(const float4*)(crow + 256 + lane * 4);
}

// ================= fallback path (R2-passing f32 pipeline) =================
__global__ __launch_bounds__(256) void csq_kernel(const float* __restrict__ cb,
                                                  float* __restrict__ csq32,
                                                  double* __restrict__ csq64,
                                                  float* __restrict__ freq,
                                                  int K) {
    int tid = threadIdx.x;
    int gt = blockIdx.x * 256 + tid;
    if (gt < K) freq[gt] = 0.0f;
    int wave = tid >> 6, lane = tid & 63;
    int k = blockIdx.x * 4 + wave;
    if (k >= K) return;
    const float* row = cb + (size_t)k * D_DIM;
    float4 v0 = *(const float4*)(row + lane * 4);
    float4 v1 = *(const float4*)(row + 256 + lane * 4);
    double s = (double)v0.x * v0.x + (double)v0.y * v0.y +
               (double)v0.z * v0.z + (double)v0.w * v0.w +
               (double)v1.x * v1.x + (double)v1.y * v1.y +
               (double)v1.z * v1.z + (double)v1.w * v1.w;
    #pragma unroll
    for (int off = 32; off > 0; off >>= 1) s += __shfl_down(s, off);
    if (lane == 0) { csq64[k] = s; csq32[k] = (float)s; }
}

__device__ __forceinline__ void top4_insert(float (&v)[4], int (&ki)[4], float s, int k) {
    if (s < v[3]) {
        v[3] = s; ki[3] = k;
        if (v[3] < v[2]) {
            float t = v[3]; v[3] = v[2]; v[2] = t; int u = ki[3]; ki[3] = ki[2]; ki[2] = u;
            if (v[2] < v[1]) {
                t = v[2]; v[2] = v[1]; v[1] = t; u = ki[2]; ki[2] = ki[1]; ki[1] = u;
                if (v[1] < v[0]) {
                    t = v[1]; v[1] = v[0]; v[0] = t; u = ki[1]; ki[1] = ki[0]; ki[0] = u;
                }
            }
        }
    }
}

#define BM 64
#define BK 128
#define BD 32
#define ZS_STRIDE (BM + 4)
#define CS_STRIDE (BK + 4)

__global__ __launch_bounds__(256) void pass1_kernel(const float* __restrict__ z,
                                                    const float* __restrict__ cb,
                                                    const float* __restrict__ csq32,
                                                    float* __restrict__ cand_v,
                                                    int* __restrict__ cand_i,
                                                    int K) {
    __shared__ float zs[BD][ZS_STRIDE];
    __shared__ float cs[BD][CS_STRIDE];
    __shared__ float mvv[BM][64];
    __shared__ int   mii[BM][64];
    const int tid = threadIdx.x;
    const int rg = tid & 15;
    const int cg = tid >> 4;
    const int row0 = blockIdx.x * BM;
    float tv[4][4]; int tk[4][4];
    #pragma unroll
    for (int r = 0; r < 4; ++r)
        #pragma unroll
        for (int m = 0; m < 4; ++m) { tv[r][m] = FLT_MAX; tk[r][m] = 0x7fffffff; }
    for (int kt = 0; kt < K; kt += BK) {
        float acc[4][8];
        #pragma unroll
        for (int r = 0; r < 4; ++r)
            #pragma unroll
            for (int cc = 0; cc < 8; ++cc) acc[r][cc] = 0.0f;
        for (int dt = 0; dt < D_DIM; dt += BD) {
            __syncthreads();
            #pragma unroll
            for (int i = 0; i < 2; ++i) {
                int lin = tid + i * 256;
                int zr = lin >> 3, dg = lin & 7;
                float4 v = *(const float4*)(z + (size_t)(row0 + zr) * D_DIM + dt + dg * 4);
                zs[dg * 4 + 0][zr] = v.x; zs[dg * 4 + 1][zr] = v.y;
                zs[dg * 4 + 2][zr] = v.z; zs[dg * 4 + 3][zr] = v.w;
            }
            #pragma unroll
            for (int i = 0; i < 4; ++i) {
                int lin = tid + i * 256;
                int cr = lin >> 3, dg = lin & 7;
                float4 v = *(const float4*)(cb + (size_t)(kt + cr) * D_DIM + dt + dg * 4);
                cs[dg * 4 + 0][cr] = v.x; cs[dg * 4 + 1][cr] = v.y;
                cs[dg * 4 + 2][cr] = v.z; cs[dg * 4 + 3][cr] = v.w;
            }
            __syncthreads();
            #pragma unroll
            for (int d = 0; d < BD; ++d) {
                float4 a = *(const float4*)&zs[d][rg * 4];
                float4 b0 = *(const float4*)&cs[d][cg * 8];
                float4 b1 = *(const float4*)&cs[d][cg * 8 + 4];
                float av[4] = {a.x, a.y, a.z, a.w};
                float bv[8] = {b0.x, b0.y, b0.z, b0.w, b1.x, b1.y, b1.z, b1.w};
                #pragma unroll
                for (int r = 0; r < 4; ++r)
                    #pragma unroll
                    for (int cc = 0; cc < 8; ++cc)
                        acc[r][cc] = fmaf(av[r], bv[cc], acc[r][cc]);
            }
        }
        #pragma unroll
        for (int cc = 0; cc < 8; ++cc) {
            int k = kt + cg * 8 + cc;
            float cq = csq32[k];
            #pragma unroll
            for (int r = 0; r < 4; ++r) {
                float s = fmaf(-2.0f, acc[r][cc], cq);
                top4_insert(tv[r], tk[r], s, k);
            }
        }
    }
    __syncthreads();
    #pragma unroll
    for (int r = 0; r < 4; ++r)
        #pragma unroll
        for (int m = 0; m < 4; ++m) {
            mvv[rg * 4 + r][cg * 4 + m] = tv[r][m];
            mii[rg * 4 + r][cg * 4 + m] = tk[r][m];
        }
    __syncthreads();
    if (tid < BM) {
        int row = tid;
        float bv[4] = {FLT_MAX, FLT_MAX, FLT_MAX, FLT_MAX};
        int   bk[4] = {0x7fffffff, 0x7fffffff, 0x7fffffff, 0x7fffffff};
        for (int j = 0; j < 64; ++j) top4_insert(bv, bk, mvv[row][j], mii[row][j]);
        #pragma unroll
        for (int m = 0; m < 4; ++m) {
            cand_v[(size_t)(row0 + row) * 4 + m] = bv[m];
            cand_i[(size_t)(row0 + row) * 4 + m] = bk[m];
        }
    }
}

__global__ __launch_bounds__(256) void pass2_kernel(const float* __restrict__ z,
                                                    const float* __restrict__ cb,
                                                    const double* __restrict__ csq64,
                                                    const float* __restrict__ cand_v,
                                                    const int* __restrict__ cand_i,
                                                    float* __restrict__ zq,
                                                    float* __restrict__ oidx,
                                                    float* __restrict__ freq,
                                                    int N, int K) {
    int lane = threadIdx.x & 63;
    int row = blockIdx.x * 4 + (threadIdx.x >> 6);
    if (row >= N) return;
    const float* zrow = z + (size_t)row * D_DIM;
    float4 z0 = *(const float4*)(zrow + lane * 4);
    float4 z1 = *(const float4*)(zrow + 256 + lane * 4);
    float cv0 = cand_v[(size_t)row * 4 + 0];
    float cv3 = cand_v[(size_t)row * 4 + 3];
    int ci[4];
    bool ok = (cv3 - cv0 >= 0.1f);
    #pragma unroll
    for (int m = 0; m < 4; ++m) {
        ci[m] = cand_i[(size_t)row * 4 + m];
        if (ci[m] < 0 || ci[m] >= K) ok = false;
    }
    double best_s = DBL_MAX;
    int best_k = 0;
    if (ok) {
        #pragma unroll
        for (int m = 0; m < 4; ++m) {
            int k = ci[m];
            const float* crow = cb + (size_t)k * D_DIM;
            float4 c0 = *(const float4*)(crow + lane * 4);
            float4 c1 = *(const float4*)(crow + 256 + lane * 4);
            double a = (double)z0.x * c0.x + (double)z0.y * c0.y +
                       (double)z0.z * c0.z + (double)z0.w * c0.w +
                       (double)z1.x * c1.x + (double)z1.y * c1.y +
                       (double)z1.z * c1.z + (double)z1.w * c1.w;
            #pragma unroll
            for (int off = 32; off > 0; off >>= 1) a += __shfl_down(a, off);
            if (lane == 0) {
                double s = csq64[k] - 2.0 * a;
                if (s < best_s || (s == best_s && k < best_k)) { best_s = s; best_k = k; }
            }
        }
    } else {
        for (int k = 0; k < K; ++k) {
            const float* crow = cb + (size_t)k * D_DIM;
            float4 c0 = *(const float4*)(crow + lane * 4);
            float4 c1 = *(const float4*)(crow + 256 + lane * 4);
            double a = (double)z0.x * c0.x + (double)z0.y * c0.y +
                       (double)z0.z * c0.z + (double)z0.w * c0.w +
                       (double)z1.x * c1.x + (double)z1.y * c1.y +
                       (double)z1.z * c1.z + (double)z1.w * c1.w;
            #pragma unroll
            for (int off = 32; off > 0; off >>= 1) a += __shfl_down(a, off);
            if (lane == 0) {
                double s = csq64[k] - 2.0 * a;
                if (s < best_s) { best_s = s; best_k = k; }
            }
        }
    }
    best_k = __shfl(best_k, 0);
    if (lane == 0) {
        oidx[row] = (float)best_k;
        atomicAdd(&freq[best_k], 1.0f);
    }
    const float* crow = cb + (size_t)best_k * D_DIM;
    *(float4*)(zq + (size_t)row * D_DIM + lane * 4) = *(const float4*)(crow + lane * 4);
    *(float4*)(zq + (size_t)row * D_DIM + 256 + lane * 4) = *(const float4*)(crow + 256 + lane * 4);
}

// ================= launcher ================================================
extern "C" void kernel_launch(void* const* d_in, const int* in_sizes, int n_in,
                              void* d_out, int out_size, void* d_ws, size_t ws_size,
                              hipStream_t stream) {
    const float* z  = (const float*)d_in[0];
    const float* cb = (const float*)d_in[1];
    const int N = in_sizes[0] / D_DIM;   // 32768
    const int K = in_sizes[1] / D_DIM;   // 4096

    float* zq   = (float*)d_out;
    float* oidx = zq + (size_t)N * D_DIM;
    float* freq = oidx + N;

    char* ws = (char*)d_ws;
    size_t o = 0;
    ushort_t* z_hi  = (ushort_t*)(ws + o); o += (size_t)N * D_DIM * 2;
    ushort_t* cbh   = (ushort_t*)(ws + o); o += (size_t)K * D_DIM * 2;
    o = (o + 255) & ~(size_t)255;
    float*  csq32   = (float*)(ws + o);    o += (size_t)K * sizeof(float);
    o = (o + 255) & ~(size_t)255;
    double* csq64   = (double*)(ws + o);   o += (size_t)K * sizeof(double);
    o = (o + 255) & ~(size_t)255;
    float* cm_v0    = (float*)(ws + o);    o += (size_t)N * 2 * sizeof(float);
    int*   cm_cnt   = (int*)(ws + o);      o += (size_t)N * 2 * sizeof(int);
    u32*   cm_mask  = (u32*)(ws + o);      o += (size_t)N * 2 * sizeof(u32);
    float* cand_vv  = (float*)(ws + o);    o += (size_t)N * 2 * 8 * sizeof(float);
    int*   cand_kk  = (int*)(ws + o);      o += (size_t)N * 2 * 8 * sizeof(int);
    size_t needed = o + 262144;            // tail-stage overrun slack

    if (ws_size >= needed && (N % 128) == 0 && K == 4096) {
        long total8 = (long)N * D_DIM / 8;
        hipLaunchKernelGGL(split_z_kernel, dim3((unsigned)((total8 + 255) / 256)), dim3(256),
                           0, stream, z, z_hi, total8);
        hipLaunchKernelGGL(split_cb_kernel, dim3(K / 4), dim3(256), 0, stream,
                           cb, cbh, csq32, csq64, freq, K);
        hipLaunchKernelGGL(pass1_mfma_kernel, dim3(N / 128, 2), dim3(256), 65536, stream,
                           z_hi, cbh, csq32, cm_v0, cm_cnt, cm_mask, cand_vv, cand_kk, K);
        hipLaunchKernelGGL(pass2_new_kernel, dim3(N / 4), dim3(256), 0, stream,
                           z, cb, csq64, cm_v0, cm_cnt, cm_mask, cand_vv, cand_kk,
                           zq, oidx, freq, N, K);
    } else {
        // R2-passing f32 fallback (small ws footprint)
        size_t o2 = 0;
        float*  f_csq32 = (float*)(ws + o2);  o2 += (size_t)K * sizeof(float);
        o2 = (o2 + 255) & ~(size_t)255;
        double* f_csq64 = (double*)(ws + o2); o2 += (size_t)K * sizeof(double);
        o2 = (o2 + 255) & ~(size_t)255;
        float*  cand_v  = (float*)(ws + o2);  o2 += (size_t)N * 4 * sizeof(float);
        int*    cand_i  = (int*)(ws + o2);
        hipLaunchKernelGGL(csq_kernel, dim3((K + 3) / 4), dim3(256), 0, stream,
                           cb, f_csq32, f_csq64, freq, K);
        hipLaunchKernelGGL(pass1_kernel, dim3(N / BM), dim3(256), 0, stream,
                           z, cb, f_csq32, cand_v, cand_i, K);
        hipLaunchKernelGGL(pass2_kernel, dim3(N / 4), dim3(256), 0, stream,
                           z, cb, f_csq64, cand_v, cand_i, zq, oidx, freq, N, K);
    }
}

// Round 19
// 237.763 us; speedup vs baseline: 1.0519x; 1.0519x over previous
//
#include <hip/hip_runtime.h>
#include <float.h>
#include <stdint.h>
#include <stddef.h>

#define D_DIM 512
// Pure bf16 hi*hi score; err = 2(e_z.c + zh.e_c), sigma ~ 0.108,
// pairwise-delta sigma ~ 0.153. MARGIN = 1.5 ~ 9.8 sigma -> miss prob ~1e-9.
#define MARGIN 1.5f

typedef unsigned short ushort_t;
typedef unsigned int u32;
typedef __attribute__((ext_vector_type(8))) short short8v;     // 8 bf16 (4 VGPRs)
typedef __attribute__((ext_vector_type(8))) unsigned short ushort8v;
typedef __attribute__((ext_vector_type(4))) float f32x4;

__device__ __forceinline__ ushort_t f32_bf16_rne(float x) {
    u32 u = __float_as_uint(x);
    u32 r = (u + 0x7fffu + ((u >> 16) & 1u)) >> 16;
    return (ushort_t)r;
}
__device__ __forceinline__ void gload_lds16(const void* g, void* l) {
    __builtin_amdgcn_global_load_lds(
        (const __attribute__((address_space(1))) u32*)(g),
        (__attribute__((address_space(3))) u32*)(l), 16, 0, 0);
}

// ============ prep (fused): z -> bf16 | codebook -> bf16 + norms + freq=0 ==
// Grid: first zblocks handle z (8 f32 -> bf16 per thread); remaining blocks
// handle the codebook (one code row per wave + norms) and zero freq.
__global__ __launch_bounds__(256) void prep_kernel(const float* __restrict__ z,
                                                   ushort_t* __restrict__ z_hi,
                                                   long ztotal8, int zblocks,
                                                   const float* __restrict__ cb,
                                                   ushort_t* __restrict__ cb_hi,
                                                   float* __restrict__ csq32,
                                                   double* __restrict__ csq64,
                                                   float* __restrict__ freq,
                                                   int K) {
    int tid = threadIdx.x;
    if (blockIdx.x < (unsigned)zblocks) {
        long i = (long)blockIdx.x * 256 + tid;
        if (i >= ztotal8) return;
        const float4* p = (const float4*)(z + i * 8);
        float4 a = p[0], b = p[1];
        float x[8] = {a.x, a.y, a.z, a.w, b.x, b.y, b.z, b.w};
        ushort8v h;
        #pragma unroll
        for (int j = 0; j < 8; ++j) h[j] = f32_bf16_rne(x[j]);
        *(ushort8v*)(z_hi + i * 8) = h;
        return;
    }
    int cblk = blockIdx.x - zblocks;
    int gt = cblk * 256 + tid;
    if (gt < K) freq[gt] = 0.0f;

    int wv = tid >> 6, lane = tid & 63;
    int k = cblk * 4 + wv;
    if (k >= K) return;
    const float* row = cb + (size_t)k * D_DIM;
    float4 a = *(const float4*)(row + lane * 8);
    float4 b = *(const float4*)(row + lane * 8 + 4);
    float x[8] = {a.x, a.y, a.z, a.w, b.x, b.y, b.z, b.w};
    ushort8v h;
    double s = 0.0;
    #pragma unroll
    for (int j = 0; j < 8; ++j) {
        s += (double)x[j] * x[j];
        h[j] = f32_bf16_rne(x[j]);
    }
    *(ushort8v*)(cb_hi + (size_t)k * D_DIM + lane * 8) = h;
    #pragma unroll
    for (int off = 32; off > 0; off >>= 1) s += __shfl_down(s, off);
    if (lane == 0) { csq64[k] = s; csq32[k] = (float)s; }
}

// ============ pass 1: bf16 MFMA GEMM + per-(row,half) candidates ===========
// R17 config (best measured: 165us): virtual K = 512, 512 thr, 256x128 tile,
// 3 LDS buffers x 48KB (144KB). Per step t:
//   STAGE(t+1)->buf[(t+1)%3]  (WAR-safe: barrier(t-1) retired COMPUTE(t-2))
//   vmcnt(6)  (drains stage(t); stage(t+1)'s 6 stay in flight)
//   s_barrier (stage(t) globally visible)
//   COMPUTE(t) on buf[t%3]
__global__ __launch_bounds__(512, 2) void pass1_mfma_kernel(
        const ushort_t* __restrict__ z_hi, const ushort_t* __restrict__ cb_hi,
        const float* __restrict__ csq32,
        float* __restrict__ cm_v0, int* __restrict__ cm_cnt,
        u32* __restrict__ cm_mask,
        float* __restrict__ cand_v, int* __restrict__ cand_k, int K) {
    extern __shared__ char smem[];
    const int tid = threadIdx.x;           // 0..511
    const int wid = tid >> 6;              // 0..7
    const int lane = tid & 63;
    const int wm = wid >> 1, wn = wid & 1; // wave grid 4x2 (64x64 tiles)
    const int c = lane & 15, g = lane >> 4;
    const int row0 = blockIdx.x * 256;
    const int half = blockIdx.y;

    // staging byte offsets (swizzle pre-applied to source)
    u32 stgA[4], stgB[2];
    #pragma unroll
    for (int r = 0; r < 4; ++r) {
        int s = r * 512 + tid, rw = s >> 3, p = s & 7;
        stgA[r] = (u32)(rw * 1024 + ((p ^ (rw & 7)) << 4));
    }
    #pragma unroll
    for (int r = 0; r < 2; ++r) {
        int s = r * 512 + tid, rw = s >> 3, p = s & 7;
        stgB[r] = (u32)(rw * 1024 + ((p ^ (rw & 7)) << 4));
    }
    // ds_read byte offsets, both k-slots precomputed
    u32 rdA[2][4], rdB[2][4];
    #pragma unroll
    for (int f = 0; f < 4; ++f) {
        int rl = wm * 64 + f * 16 + c;                 // 0..255
        rdA[0][f] = (u32)(rl * 128 + ((g ^ (rl & 7)) << 4));
        rdA[1][f] = rdA[0][f] ^ 64u;
        int cl = wn * 64 + f * 16 + c;                 // 0..127
        rdB[0][f] = (u32)(cl * 128 + ((g ^ (cl & 7)) << 4));
        rdB[1][f] = rdB[0][f] ^ 64u;
    }

    const char* pA = (const char*)z_hi + (size_t)row0 * 1024;
    const char* pB = (const char*)cb_hi + (size_t)half * 2048 * 1024;

    // after staging chunk 7: next stage is chunk 0 of the NEXT code tile
    const ptrdiff_t eA7 = -896;            // zh+896 -> zh+0 (A reused per ct)
    const ptrdiff_t eB7 = 131072 - 896;    // ch+896 -> next-ct ch+0

    f32x4 acc[4][4];
    float tv0[16], tv1[16]; int tk0[16];
    #pragma unroll
    for (int i = 0; i < 16; ++i) { tv0[i] = FLT_MAX; tv1[i] = FLT_MAX; tk0[i] = 0; }

    auto STAGE = [&](u32 off) {
        char* base = smem + off;
        #pragma unroll
        for (int r = 0; r < 4; ++r)
            gload_lds16(pA + stgA[r], base + r * 8192 + wid * 1024);
        #pragma unroll
        for (int r = 0; r < 2; ++r)
            gload_lds16(pB + stgB[r], base + 32768 + r * 8192 + wid * 1024);
    };
    auto COMPUTE = [&](u32 off) {
        const char* Abase = smem + off;
        const char* Bb = Abase + 32768;
        #pragma unroll
        for (int ks = 0; ks < 2; ++ks) {
            short8v a[4], b[4];
            #pragma unroll
            for (int f = 0; f < 4; ++f) a[f] = *(const short8v*)(Abase + rdA[ks][f]);
            #pragma unroll
            for (int f = 0; f < 4; ++f) b[f] = *(const short8v*)(Bb + rdB[ks][f]);
            #pragma unroll
            for (int fm = 0; fm < 4; ++fm)
                #pragma unroll
                for (int fn = 0; fn < 4; ++fn)
                    acc[fm][fn] = __builtin_amdgcn_mfma_f32_16x16x32_bf16(
                        a[fm], b[fn], acc[fm][fn], 0, 0, 0);
        }
    };
    auto WAITBAR = [&]() {
        asm volatile("s_waitcnt vmcnt(6)" ::: "memory");
        __builtin_amdgcn_s_barrier();
        __builtin_amdgcn_sched_barrier(0);
    };

    // prologue: stage chunk 0 -> buf0
    STAGE(0); pA += 128; pB += 128;
    u32 offS = 49152;                      // next stage buffer
    u32 offC = 0;                          // next compute buffer

    #pragma unroll 1
    for (int ci = 0; ci < 16; ++ci) {
        int code0 = (half * 16 + ci) << 7;
        float cq[4];
        #pragma unroll
        for (int fn = 0; fn < 4; ++fn) cq[fn] = csq32[code0 + wn * 64 + fn * 16 + c];

        f32x4 zz = {0.f, 0.f, 0.f, 0.f};
        #pragma unroll
        for (int fm = 0; fm < 4; ++fm)
            #pragma unroll
            for (int fn = 0; fn < 4; ++fn) acc[fm][fn] = zz;

        // 8 steps; ct-advance after staging chunk 7 (t==6).
        #pragma unroll 1
        for (int t = 0; t < 8; ++t) {
            STAGE(offS);
            { ptrdiff_t dA = 128, dB = 128;
              if (t == 6) { dA = eA7; dB = eB7; }
              pA += dA; pB += dB; }
            WAITBAR();
            COMPUTE(offC);
            offS = (offS == 98304u) ? 0u : offS + 49152u;
            offC = (offC == 98304u) ? 0u : offC + 49152u;
        }
        // (t==7 staged chunk0 of next ct; for ci==15 it reads in-bounds
        //  trailing ws data that is never consumed)

        // ---- epilogue: scores + branchless top-2 value + top-1 index ----
        #pragma unroll
        for (int fm = 0; fm < 4; ++fm)
            #pragma unroll
            for (int fn = 0; fn < 4; ++fn) {
                int code = code0 + wn * 64 + fn * 16 + c;
                #pragma unroll
                for (int rg = 0; rg < 4; ++rg) {
                    int rp = fm * 4 + rg;
                    float sv = fmaf(-2.0f, acc[fm][fn][rg], cq[fn]);
                    bool b0 = sv < tv0[rp];
                    bool b1 = sv < tv1[rp];
                    tv1[rp] = b0 ? tv0[rp] : (b1 ? sv : tv1[rp]);
                    tv0[rp] = b0 ? sv : tv0[rp];
                    tk0[rp] = b0 ? code : tk0[rp];
                }
            }
    }

    // ---- merge 32 slots/row (top-1 idx + top-2 values) for this half ----
    __syncthreads();                       // full drain (incl. tail stage)
    float* mv = (float*)smem;              // [256][64]: even=v0, odd=v1 (64KB)
    int*   mi = (int*)(smem + 65536);      // [256][32]: top-1 codes (32KB)
    #pragma unroll
    for (int fm = 0; fm < 4; ++fm)
        #pragma unroll
        for (int rg = 0; rg < 4; ++rg) {
            int rl = wm * 64 + fm * 16 + g * 4 + rg;   // C row mapping 0..255
            int slot = wn * 16 + c;                    // 0..31
            int rp = fm * 4 + rg;
            mv[rl * 64 + slot * 2]     = tv0[rp];
            mv[rl * 64 + slot * 2 + 1] = tv1[rp];
            mi[rl * 32 + slot]         = tk0[rp];
        }
    __syncthreads();
    if (tid < 256) {
        const float* rv = mv + tid * 64;
        const int*   ri = mi + tid * 32;
        float v0 = FLT_MAX;
        #pragma unroll 8
        for (int j = 0; j < 32; ++j) v0 = fminf(v0, rv[2 * j]);
        float lim = v0 + MARGIN;
        u32 mask = 0;
        int cnt = 0; int ks[8]; float vs[8];
        for (int j = 0; j < 32; ++j) {
            if (rv[2 * j] <= lim) {
                if (cnt < 8) { ks[cnt] = ri[j]; vs[cnt] = rv[2 * j]; cnt++; }
                else mask |= 1u << j;      // overflow: rescan this slot
            }
            if (rv[2 * j + 1] <= lim) mask |= 1u << j;  // slot-second in margin
        }
        int gidx = (row0 + tid) * 2 + half;
        cm_v0[gidx]  = v0;
        cm_cnt[gidx] = cnt;                // always 1..8
        cm_mask[gidx] = mask;
        for (int m = 0; m < cnt; ++m) {
            cand_v[(size_t)gidx * 8 + m] = vs[m];
            cand_k[(size_t)gidx * 8 + m] = ks[m];
        }
    }
}

// ============ pass 2: merge halves, f64 rescore (cands + suspect slots) ====
__global__ __launch_bounds__(256) void pass2_new_kernel(
        const float* __restrict__ z, const float* __restrict__ cb,
        const double* __restrict__ csq64,
        const float* __restrict__ cm_v0, const int* __restrict__ cm_cnt,
        const u32* __restrict__ cm_mask,
        const float* __restrict__ cand_v, const int* __restrict__ cand_k,
        float* __restrict__ zq, float* __restrict__ oidx, float* __restrict__ freq,
        int N, int K) {
    int lane = threadIdx.x & 63;
    int row = blockIdx.x * 4 + (threadIdx.x >> 6);
    if (row >= N) return;
    const int Khalf = K >> 1;              // 2048

    float v0a = cm_v0[row * 2], v0b = cm_v0[row * 2 + 1];
    int   na  = cm_cnt[row * 2], nb = cm_cnt[row * 2 + 1];
    u32   ma  = cm_mask[row * 2], mb = cm_mask[row * 2 + 1];
    float lim = fminf(v0a, v0b) + MARGIN;
    if (na > 8 || na < 0) { na = 0; ma = 0xffffffffu; }   // defensive
    if (nb > 8 || nb < 0) { nb = 0; mb = 0xffffffffu; }

    // collect stored candidates <= global lim
    int ks[16]; int cnt = 0;
    {
        for (int m = 0; m < na; ++m) {
            size_t idx = (size_t)(row * 2) * 8 + m;
            if (cand_v[idx] <= lim) ks[cnt++] = cand_k[idx];
        }
        for (int m = 0; m < nb; ++m) {
            size_t idx = (size_t)(row * 2 + 1) * 8 + m;
            if (cand_v[idx] <= lim) ks[cnt++] = cand_k[idx];
        }
    }

    int best_k;
    if (cnt == 1 && ma == 0 && mb == 0) {
        best_k = ks[0];                    // exact within margin model
    } else {
        const float* zrow = z + (size_t)row * D_DIM;
        double best_s = DBL_MAX; int bk = 0x7fffffff;

        // phase 1: rescore candidate list (64-lane d-split per code)
        {
            float4 z0 = *(const float4*)(zrow + lane * 4);
            float4 z1 = *(const float4*)(zrow + 256 + lane * 4);
            for (int m = 0; m < cnt; ++m) {
                int k = ks[m];
                const float* crow = cb + (size_t)k * D_DIM;
                float4 c0 = *(const float4*)(crow + lane * 4);
                float4 c1 = *(const float4*)(crow + 256 + lane * 4);
                double a = (double)z0.x * c0.x + (double)z0.y * c0.y +
                           (double)z0.z * c0.z + (double)z0.w * c0.w +
                           (double)z1.x * c1.x + (double)z1.y * c1.y +
                           (double)z1.z * c1.z + (double)z1.w * c1.w;
                #pragma unroll
                for (int off = 32; off > 0; off >>= 1) a += __shfl_down(a, off);
                if (lane == 0) {
                    double s = csq64[k] - 2.0 * a;
                    if (s < best_s || (s == best_s && k < bk)) { best_s = s; bk = k; }
                }
            }
            best_s = __shfl(best_s, 0);
            bk     = __shfl(bk, 0);
        }

        // phase 2: rescan suspect slots (64 codes each; 8 codes x 8 lanes)
        if (ma | mb) {
            const int cs = lane >> 3;      // code sub-index 0..7
            const int ds = lane & 7;       // d-chunk 0..7 (64 floats each)
            const float* zch = zrow + ds * 64;
            float4 zr[16];
            #pragma unroll
            for (int j = 0; j < 16; ++j) zr[j] = *(const float4*)(zch + j * 4);

            double bs2 = DBL_MAX; int bk2 = 0x7fffffff;
            for (int h = 0; h < 2; ++h) {
                u32 m = h ? mb : ma;
                while (m) {
                    int s = __ffs(m) - 1; m &= m - 1;
                    for (int tb = 0; tb < 8; ++tb) {
                        int t = tb * 8 + cs;                       // 0..63
                        int code = h * Khalf + ((t >> 2) << 7) + ((s >> 4) << 6)
                                 + ((t & 3) << 4) + (s & 15);
                        const float* crow = cb + (size_t)code * D_DIM + ds * 64;
                        double a0 = 0.0, a1 = 0.0, a2 = 0.0, a3 = 0.0;
                        #pragma unroll
                        for (int j = 0; j < 16; j += 4) {
                            float4 c0 = *(const float4*)(crow + j * 4);
                            float4 c1 = *(const float4*)(crow + j * 4 + 4);
                            float4 c2 = *(const float4*)(crow + j * 4 + 8);
                            float4 c3 = *(const float4*)(crow + j * 4 + 12);
                            a0 += (double)zr[j].x * c0.x + (double)zr[j].y * c0.y +
                                  (double)zr[j].z * c0.z + (double)zr[j].w * c0.w;
                            a1 += (double)zr[j+1].x * c1.x + (double)zr[j+1].y * c1.y +
                                  (double)zr[j+1].z * c1.z + (double)zr[j+1].w * c1.w;
                            a2 += (double)zr[j+2].x * c2.x + (double)zr[j+2].y * c2.y +
                                  (double)zr[j+2].z * c2.z + (double)zr[j+2].w * c2.w;
                            a3 += (double)zr[j+3].x * c3.x + (double)zr[j+3].y * c3.y +
                                  (double)zr[j+3].z * c3.z + (double)zr[j+3].w * c3.w;
                        }
                        double a = (a0 + a1) + (a2 + a3);
                        #pragma unroll
                        for (int off = 1; off < 8; off <<= 1) a += __shfl_xor(a, off);
                        double sc = csq64[code] - 2.0 * a;
                        if (sc < bs2 || (sc == bs2 && code < bk2)) { bs2 = sc; bk2 = code; }
                    }
                }
            }
            #pragma unroll
            for (int off = 32; off > 0; off >>= 1) {
                double os = __shfl_down(bs2, off);
                int    ok2 = __shfl_down(bk2, off);
                if (os < bs2 || (os == bs2 && ok2 < bk2)) { bs2 = os; bk2 = ok2; }
            }
            bs2 = __shfl(bs2, 0);
            bk2 = __shfl(bk2, 0);
            if (bs2 < best_s || (bs2 == best_s && bk2 < bk)) { best_s = bs2; bk = bk2; }
        }
        best_k = bk;
    }

    if (lane == 0) {
        oidx[row] = (float)best_k;
        atomicAdd(&freq[best_k], 1.0f);
    }
    // gather z_q = codebook[best_k] (exact -> bitwise match)
    const float* crow = cb + (size_t)best_k * D_DIM;
    *(float4*)(zq + (size_t)row * D_DIM + lane * 4) = *(const float4*)(crow + lane * 4);
    *(float4*)(zq + (size_t)row * D_DIM + 256 + lane * 4) = *(const float4*)(crow + 256 + lane * 4);
}

// ================= fallback path (R2-passing f32 pipeline) =================
__global__ __launch_bounds__(256) void csq_kernel(const float* __restrict__ cb,
                                                  float* __restrict__ csq32,
                                                  double* __restrict__ csq64,
                                                  float* __restrict__ freq,
                                                  int K) {
    int tid = threadIdx.x;
    int gt = blockIdx.x * 256 + tid;
    if (gt < K) freq[gt] = 0.0f;
    int wave = tid >> 6, lane = tid & 63;
    int k = blockIdx.x * 4 + wave;
    if (k >= K) return;
    const float* row = cb + (size_t)k * D_DIM;
    float4 v0 = *(const float4*)(row + lane * 4);
    float4 v1 = *(const float4*)(row + 256 + lane * 4);
    double s = (double)v0.x * v0.x + (double)v0.y * v0.y +
               (double)v0.z * v0.z + (double)v0.w * v0.w +
               (double)v1.x * v1.x + (double)v1.y * v1.y +
               (double)v1.z * v1.z + (double)v1.w * v1.w;
    #pragma unroll
    for (int off = 32; off > 0; off >>= 1) s += __shfl_down(s, off);
    if (lane == 0) { csq64[k] = s; csq32[k] = (float)s; }
}

__device__ __forceinline__ void top4_insert(float (&v)[4], int (&ki)[4], float s, int k) {
    if (s < v[3]) {
        v[3] = s; ki[3] = k;
        if (v[3] < v[2]) {
            float t = v[3]; v[3] = v[2]; v[2] = t; int u = ki[3]; ki[3] = ki[2]; ki[2] = u;
            if (v[2] < v[1]) {
                t = v[2]; v[2] = v[1]; v[1] = t; u = ki[2]; ki[2] = ki[1]; ki[1] = u;
                if (v[1] < v[0]) {
                    t = v[1]; v[1] = v[0]; v[0] = t; u = ki[1]; ki[1] = ki[0]; ki[0] = u;
                }
            }
        }
    }
}

#define BM 64
#define BK 128
#define BD 32
#define ZS_STRIDE (BM + 4)
#define CS_STRIDE (BK + 4)

__global__ __launch_bounds__(256) void pass1_kernel(const float* __restrict__ z,
                                                    const float* __restrict__ cb,
                                                    const float* __restrict__ csq32,
                                                    float* __restrict__ cand_v,
                                                    int* __restrict__ cand_i,
                                                    int K) {
    __shared__ float zs[BD][ZS_STRIDE];
    __shared__ float cs[BD][CS_STRIDE];
    __shared__ float mvv[BM][64];
    __shared__ int   mii[BM][64];
    const int tid = threadIdx.x;
    const int rg = tid & 15;
    const int cg = tid >> 4;
    const int row0 = blockIdx.x * BM;
    float tv[4][4]; int tk[4][4];
    #pragma unroll
    for (int r = 0; r < 4; ++r)
        #pragma unroll
        for (int m = 0; m < 4; ++m) { tv[r][m] = FLT_MAX; tk[r][m] = 0x7fffffff; }
    for (int kt = 0; kt < K; kt += BK) {
        float acc[4][8];
        #pragma unroll
        for (int r = 0; r < 4; ++r)
            #pragma unroll
            for (int cc = 0; cc < 8; ++cc) acc[r][cc] = 0.0f;
        for (int dt = 0; dt < D_DIM; dt += BD) {
            __syncthreads();
            #pragma unroll
            for (int i = 0; i < 2; ++i) {
                int lin = tid + i * 256;
                int zr = lin >> 3, dg = lin & 7;
                float4 v = *(const float4*)(z + (size_t)(row0 + zr) * D_DIM + dt + dg * 4);
                zs[dg * 4 + 0][zr] = v.x; zs[dg * 4 + 1][zr] = v.y;
                zs[dg * 4 + 2][zr] = v.z; zs[dg * 4 + 3][zr] = v.w;
            }
            #pragma unroll
            for (int i = 0; i < 4; ++i) {
                int lin = tid + i * 256;
                int cr = lin >> 3, dg = lin & 7;
                float4 v = *(const float4*)(cb + (size_t)(kt + cr) * D_DIM + dt + dg * 4);
                cs[dg * 4 + 0][cr] = v.x; cs[dg * 4 + 1][cr] = v.y;
                cs[dg * 4 + 2][cr] = v.z; cs[dg * 4 + 3][cr] = v.w;
            }
            __syncthreads();
            #pragma unroll
            for (int d = 0; d < BD; ++d) {
                float4 a = *(const float4*)&zs[d][rg * 4];
                float4 b0 = *(const float4*)&cs[d][cg * 8];
                float4 b1 = *(const float4*)&cs[d][cg * 8 + 4];
                float av[4] = {a.x, a.y, a.z, a.w};
                float bv[8] = {b0.x, b0.y, b0.z, b0.w, b1.x, b1.y, b1.z, b1.w};
                #pragma unroll
                for (int r = 0; r < 4; ++r)
                    #pragma unroll
                    for (int cc = 0; cc < 8; ++cc)
                        acc[r][cc] = fmaf(av[r], bv[cc], acc[r][cc]);
            }
        }
        #pragma unroll
        for (int cc = 0; cc < 8; ++cc) {
            int k = kt + cg * 8 + cc;
            float cq = csq32[k];
            #pragma unroll
            for (int r = 0; r < 4; ++r) {
                float s = fmaf(-2.0f, acc[r][cc], cq);
                top4_insert(tv[r], tk[r], s, k);
            }
        }
    }
    __syncthreads();
    #pragma unroll
    for (int r = 0; r < 4; ++r)
        #pragma unroll
        for (int m = 0; m < 4; ++m) {
            mvv[rg * 4 + r][cg * 4 + m] = tv[r][m];
            mii[rg * 4 + r][cg * 4 + m] = tk[r][m];
        }
    __syncthreads();
    if (tid < BM) {
        int row = tid;
        float bv[4] = {FLT_MAX, FLT_MAX, FLT_MAX, FLT_MAX};
        int   bk[4] = {0x7fffffff, 0x7fffffff, 0x7fffffff, 0x7fffffff};
        for (int j = 0; j < 64; ++j) top4_insert(bv, bk, mvv[row][j], mii[row][j]);
        #pragma unroll
        for (int m = 0; m < 4; ++m) {
            cand_v[(size_t)(row0 + row) * 4 + m] = bv[m];
            cand_i[(size_t)(row0 + row) * 4 + m] = bk[m];
        }
    }
}

__global__ __launch_bounds__(256) void pass2_kernel(const float* __restrict__ z,
                                                    const float* __restrict__ cb,
                                                    const double* __restrict__ csq64,
                                                    const float* __restrict__ cand_v,
                                                    const int* __restrict__ cand_i,
                                                    float* __restrict__ zq,
                                                    float* __restrict__ oidx,
                                                    float* __restrict__ freq,
                                                    int N, int K) {
    int lane = threadIdx.x & 63;
    int row = blockIdx.x * 4 + (threadIdx.x >> 6);
    if (row >= N) return;
    const float* zrow = z + (size_t)row * D_DIM;
    float4 z0 = *(const float4*)(zrow + lane * 4);
    float4 z1 = *(const float4*)(zrow + 256 + lane * 4);
    float cv0 = cand_v[(size_t)row * 4 + 0];
    float cv3 = cand_v[(size_t)row * 4 + 3];
    int ci[4];
    bool ok = (cv3 - cv0 >= 0.1f);
    #pragma unroll
    for (int m = 0; m < 4; ++m) {
        ci[m] = cand_i[(size_t)row * 4 + m];
        if (ci[m] < 0 || ci[m] >= K) ok = false;
    }
    double best_s = DBL_MAX;
    int best_k = 0;
    if (ok) {
        #pragma unroll
        for (int m = 0; m < 4; ++m) {
            int k = ci[m];
            const float* crow = cb + (size_t)k * D_DIM;
            float4 c0 = *(const float4*)(crow + lane * 4);
            float4 c1 = *(const float4*)(crow + 256 + lane * 4);
            double a = (double)z0.x * c0.x + (double)z0.y * c0.y +
                       (double)z0.z * c0.z + (double)z0.w * c0.w +
                       (double)z1.x * c1.x + (double)z1.y * c1.y +
                       (double)z1.z * c1.z + (double)z1.w * c1.w;
            #pragma unroll
            for (int off = 32; off > 0; off >>= 1) a += __shfl_down(a, off);
            if (lane == 0) {
                double s = csq64[k] - 2.0 * a;
                if (s < best_s || (s == best_s && k < best_k)) { best_s = s; best_k = k; }
            }
        }
    } else {
        for (int k = 0; k < K; ++k) {
            const float* crow = cb + (size_t)k * D_DIM;
            float4 c0 = *(const float4*)(crow + lane * 4);
            float4 c1 = *(const float4*)(crow + 256 + lane * 4);
            double a = (double)z0.x * c0.x + (double)z0.y * c0.y +
                       (double)z0.z * c0.z + (double)z0.w * c0.w +
                       (double)z1.x * c1.x + (double)z1.y * c1.y +
                       (double)z1.z * c1.z + (double)z1.w * c1.w;
            #pragma unroll
            for (int off = 32; off > 0; off >>= 1) a += __shfl_down(a, off);
            if (lane == 0) {
                double s = csq64[k] - 2.0 * a;
                if (s < best_s) { best_s = s; best_k = k; }
            }
        }
    }
    best_k = __shfl(best_k, 0);
    if (lane == 0) {
        oidx[row] = (float)best_k;
        atomicAdd(&freq[best_k], 1.0f);
    }
    const float* crow = cb + (size_t)best_k * D_DIM;
    *(float4*)(zq + (size_t)row * D_DIM + lane * 4) = *(const float4*)(crow + lane * 4);
    *(float4*)(zq + (size_t)row * D_DIM + 256 + lane * 4) = *(const float4*)(crow + 256 + lane * 4);
}

// ================= launcher ================================================
extern "C" void kernel_launch(void* const* d_in, const int* in_sizes, int n_in,
                              void* d_out, int out_size, void* d_ws, size_t ws_size,
                              hipStream_t stream) {
    const float* z  = (const float*)d_in[0];
    const float* cb = (const float*)d_in[1];
    const int N = in_sizes[0] / D_DIM;   // 32768
    const int K = in_sizes[1] / D_DIM;   // 4096

    float* zq   = (float*)d_out;
    float* oidx = zq + (size_t)N * D_DIM;
    float* freq = oidx + N;

    char* ws = (char*)d_ws;
    size_t o = 0;
    ushort_t* z_hi  = (ushort_t*)(ws + o); o += (size_t)N * D_DIM * 2;
    ushort_t* cbh   = (ushort_t*)(ws + o); o += (size_t)K * D_DIM * 2;
    o = (o + 255) & ~(size_t)255;
    float*  csq32   = (float*)(ws + o);    o += (size_t)K * sizeof(float);
    o = (o + 255) & ~(size_t)255;
    double* csq64   = (double*)(ws + o);   o += (size_t)K * sizeof(double);
    o = (o + 255) & ~(size_t)255;
    float* cm_v0    = (float*)(ws + o);    o += (size_t)N * 2 * sizeof(float);
    int*   cm_cnt   = (int*)(ws + o);      o += (size_t)N * 2 * sizeof(int);
    u32*   cm_mask  = (u32*)(ws + o);      o += (size_t)N * 2 * sizeof(u32);
    float* cand_vv  = (float*)(ws + o);    o += (size_t)N * 2 * 8 * sizeof(float);
    int*   cand_kk  = (int*)(ws + o);      o += (size_t)N * 2 * 8 * sizeof(int);
    size_t needed = o + 262144;            // tail-stage overrun slack

    if (ws_size >= needed && (N % 256) == 0 && K == 4096) {
        hipFuncSetAttribute((const void*)pass1_mfma_kernel,
                            hipFuncAttributeMaxDynamicSharedMemorySize, 147456);
        long total8 = (long)N * D_DIM / 8;
        int zblocks = (int)((total8 + 255) / 256);
        int cblocks = K / 4;
        hipLaunchKernelGGL(prep_kernel, dim3(zblocks + cblocks), dim3(256), 0, stream,
                           z, z_hi, total8, zblocks, cb, cbh, csq32, csq64, freq, K);
        hipLaunchKernelGGL(pass1_mfma_kernel, dim3(N / 256, 2), dim3(512), 147456, stream,
                           z_hi, cbh, csq32, cm_v0, cm_cnt, cm_mask, cand_vv, cand_kk, K);
        hipLaunchKernelGGL(pass2_new_kernel, dim3(N / 4), dim3(256), 0, stream,
                           z, cb, csq64, cm_v0, cm_cnt, cm_mask, cand_vv, cand_kk,
                           zq, oidx, freq, N, K);
    } else {
        // R2-passing f32 fallback (small ws footprint)
        size_t o2 = 0;
        float*  f_csq32 = (float*)(ws + o2);  o2 += (size_t)K * sizeof(float);
        o2 = (o2 + 255) & ~(size_t)255;
        double* f_csq64 = (double*)(ws + o2); o2 += (size_t)K * sizeof(double);
        o2 = (o2 + 255) & ~(size_t)255;
        float*  cand_v  = (float*)(ws + o2);  o2 += (size_t)N * 4 * sizeof(float);
        int*    cand_i  = (int*)(ws + o2);
        hipLaunchKernelGGL(csq_kernel, dim3((K + 3) / 4), dim3(256), 0, stream,
                           cb, f_csq32, f_csq64, freq, K);
        hipLaunchKernelGGL(pass1_kernel, dim3(N / BM), dim3(256), 0, stream,
                           z, cb, f_csq32, cand_v, cand_i, K);
        hipLaunchKernelGGL(pass2_kernel, dim3(N / 4), dim3(256), 0, stream,
                           z, cb, f_csq64, cand_v, cand_i, zq, oidx, freq, N, K);
    }
}